// Round 1
// baseline (555.439 us; speedup 1.0000x reference)
//
#include <hip/hip_runtime.h>

#define Bb 8
#define Tt 512
#define Uu 128
#define U1 129
#define Vv 128
#define SKD 640   // T + U : skew diagonal count

// ws layout in floats
#define BLANK_SKEW_OFF 0
#define BLANK_SKEW_SZ (Bb*SKD*U1)
#define EMIT_SKEW_OFF (BLANK_SKEW_SZ)
#define EMIT_SKEW_SZ (Bb*SKD*Uu)
#define RES_OFF (BLANK_SKEW_OFF + BLANK_SKEW_SZ + EMIT_SKEW_SZ)

// One wave per (b,t,u) row of V=128 logits: logsumexp reduce, write
// blank/emit log-probs into skewed [b][t+u][u] layout so dp_kernel's
// diagonal reads are contiguous.
__global__ __launch_bounds__(256) void lse_kernel(
    const float* __restrict__ logits, const int* __restrict__ y,
    float* __restrict__ ws)
{
    const int wid  = threadIdx.x >> 6;
    const int lane = threadIdx.x & 63;
    const long long row = (long long)blockIdx.x * 4 + wid;

    const int TU = Tt * U1;
    int b   = (int)(row / TU);
    int rem = (int)(row - (long long)b * TU);
    int t   = rem / U1;
    int u   = rem - t * U1;

    const float* p = logits + row * Vv;
    float2 v = *(const float2*)(p + lane * 2);

    float m = fmaxf(v.x, v.y);
    #pragma unroll
    for (int off = 32; off; off >>= 1)
        m = fmaxf(m, __shfl_xor(m, off));
    float s = __expf(v.x - m) + __expf(v.y - m);
    #pragma unroll
    for (int off = 32; off; off >>= 1)
        s += __shfl_xor(s, off);
    float lse = m + __logf(s);

    float* blank_skew = ws + BLANK_SKEW_OFF;
    float* emit_skew  = ws + EMIT_SKEW_OFF;
    const int d = t + u;
    if (lane == 0) {
        blank_skew[((size_t)b * SKD + d) * U1 + u] = v.x - lse;
    }
    if (u < Uu) {
        int yv = y[b * Uu + u];        // in [1, V)
        if (lane == (yv >> 1)) {
            float ev = (yv & 1) ? v.y : v.x;
            emit_skew[((size_t)b * SKD + d) * Uu + u] = ev - lse;
        }
    }
}

// One block per batch. Anti-diagonal wavefront over the (t,u) grid.
// diag d holds cells (d-u, u); cell needs prev-diag[u] (below) and
// prev-diag[u-1] (left). -inf sentinels outside the valid band.
__global__ __launch_bounds__(192) void dp_kernel(
    const int* __restrict__ logit_lens, const int* __restrict__ y_lens,
    float* __restrict__ ws)
{
    const int b = blockIdx.x;
    const int u = threadIdx.x;
    const int Tb = logit_lens[b];
    const int Ub = y_lens[b];
    const float* blank_skew = ws + BLANK_SKEW_OFF + (size_t)b * SKD * U1;
    const float* emit_skew  = ws + EMIT_SKEW_OFF + (size_t)b * SKD * Uu;

    __shared__ float diag[2][U1];
    const float NEG = -__builtin_inff();

    if (u <= Uu) { diag[0][u] = (u == 0) ? 0.0f : NEG; diag[1][u] = NEG; }
    __syncthreads();

    const int dend = Tb - 1 + Ub;
    for (int d = 1; d <= dend; ++d) {
        const int cur = d & 1, prv = cur ^ 1;
        if (u <= Uu) {
            float val = NEG;
            int lo = d - (Tb - 1); if (lo < 0) lo = 0;
            int hi = (d < Ub) ? d : Ub;
            if (u >= lo && u <= hi) {
                const int t = d - u;
                float below = diag[prv][u];
                float left  = (u >= 1) ? diag[prv][u - 1] : NEG;
                float bl = (t >= 1) ? blank_skew[(size_t)(d - 1) * U1 + u] : 0.0f;
                float em = (u >= 1) ? emit_skew[(size_t)(d - 1) * Uu + (u - 1)] : 0.0f;
                float x  = below + bl;
                float yv = left + em;
                float mx = fmaxf(x, yv);
                val = (mx == NEG) ? NEG
                                  : mx + log1pf(__expf(fminf(x, yv) - mx));
                if (d == dend && u == Ub) {
                    float blk = blank_skew[(size_t)dend * U1 + Ub];
                    ws[RES_OFF + b] = -(val + blk);
                }
            }
            diag[cur][u] = val;
        }
        __syncthreads();
    }
}

__global__ void mean_kernel(const float* __restrict__ res, float* __restrict__ out)
{
    if (threadIdx.x == 0) {
        float s = 0.0f;
        #pragma unroll
        for (int i = 0; i < Bb; ++i) s += res[i];
        out[0] = s * (1.0f / Bb);
    }
}

extern "C" void kernel_launch(void* const* d_in, const int* in_sizes, int n_in,
                              void* d_out, int out_size, void* d_ws, size_t ws_size,
                              hipStream_t stream) {
    const float* logits     = (const float*)d_in[0];
    const int*   y          = (const int*)d_in[1];
    const int*   logit_lens = (const int*)d_in[2];
    const int*   y_lens     = (const int*)d_in[3];
    float* ws  = (float*)d_ws;
    float* out = (float*)d_out;

    const int rows = Bb * Tt * U1;          // 528384 rows, 4 waves/block
    lse_kernel<<<rows / 4, 256, 0, stream>>>(logits, y, ws);
    dp_kernel<<<Bb, 192, 0, stream>>>(logit_lens, y_lens, ws);
    mean_kernel<<<1, 64, 0, stream>>>(ws + RES_OFF, out);
}

// Round 2
// 297.509 us; speedup vs baseline: 1.8670x; 1.8670x over previous
//
#include <hip/hip_runtime.h>

#define Bb 8
#define Tt 512
#define Uu 128
#define U1 129
#define Vv 128
#define SKD 640   // T + U : skew diagonal count

// ws layout in floats: blank_skew [B][SKD][U1], emit_skew [B][SKD][U1]
// blank_skew[b][t+u][u]     = log_softmax(logits[b,t,u,:])[0]
// emit_skew [b][t+u+1][u+1] = log_softmax(logits[b,t,u,:])[y[b,u]]  (u<Uu)
#define BLANK_SKEW_OFF 0
#define REGION_SZ (Bb*SKD*U1)
#define EMIT_SKEW_OFF (REGION_SZ)
#define RES_OFF (2*REGION_SZ)

// Each half-wave (32 lanes) handles one 128-wide logits row via float4.
__global__ __launch_bounds__(256) void lse_kernel(
    const float* __restrict__ logits, const int* __restrict__ y,
    float* __restrict__ ws)
{
    const int wid  = threadIdx.x >> 6;
    const int lane = threadIdx.x & 63;
    const int half = lane >> 5;        // 0/1: which row of this wave
    const int hl   = lane & 31;

    const long long row = (long long)blockIdx.x * 8 + wid * 2 + half;
    const int TU = Tt * U1;
    int b   = (int)(row / TU);
    int rem = (int)(row - (long long)b * TU);
    int t   = rem / U1;
    int u   = rem - t * U1;

    const float* p = logits + row * Vv + hl * 4;
    float4 v = *(const float4*)p;

    float m = fmaxf(fmaxf(v.x, v.y), fmaxf(v.z, v.w));
    #pragma unroll
    for (int off = 16; off; off >>= 1)
        m = fmaxf(m, __shfl_xor(m, off));
    float s = __expf(v.x - m) + __expf(v.y - m) + __expf(v.z - m) + __expf(v.w - m);
    #pragma unroll
    for (int off = 16; off; off >>= 1)
        s += __shfl_xor(s, off);
    float lse = m + __logf(s);

    float* BL = ws + BLANK_SKEW_OFF;
    float* EM = ws + EMIT_SKEW_OFF;
    if (hl == 0) {
        BL[((size_t)b * SKD + (t + u)) * U1 + u] = v.x - lse;
    }
    if (u < Uu) {
        int yv = y[b * Uu + u];            // in [1, V)
        if (hl == (yv >> 2)) {
            int c = yv & 3;
            float ev = (c == 0) ? v.x : (c == 1) ? v.y : (c == 2) ? v.z : v.w;
            EM[((size_t)b * SKD + (t + u + 1)) * U1 + (u + 1)] = ev - lse;
        }
    }
}

__device__ __forceinline__ float lae(float x, float y) {
    float mx = fmaxf(x, y), mn = fminf(x, y);
    float r = mx + __logf(1.0f + __expf(mn - mx));
    return (mx == -__builtin_inff()) ? -__builtin_inff() : r;
}

#define LOADD(P, dd) { \
    const float* blr = BL + (size_t)((dd) - 1) * U1; \
    const float* emr = EM + (size_t)(dd) * U1; \
    P##b0 = blr[lane]; P##b1 = blr[64 + lane]; P##b2 = blr[128]; \
    P##e0 = emr[lane]; P##e1 = emr[64 + lane]; P##e2 = emr[128]; \
}

#define COMPUTE(P, dd) { \
    int lo = (dd) - (Tb - 1); lo = lo < 0 ? 0 : lo; \
    int hi = (dd) < Ub ? (dd) : Ub; \
    float pm0 = __shfl_up(p0, 1); \
    float pm1 = __shfl_up(p1, 1); \
    float t63 = __shfl(p0, 63); \
    float pm2 = __shfl(p1, 63); \
    if (lane == 0) pm1 = t63; \
    float x0 = p0 + P##b0, y0 = (lane == 0) ? NEG : pm0 + P##e0; \
    float x1 = p1 + P##b1, y1 = pm1 + P##e1; \
    float x2 = p2 + P##b2, y2 = pm2 + P##e2; \
    float v0 = lae(x0, y0), v1 = lae(x1, y1), v2 = lae(x2, y2); \
    p0 = (lane >= lo && lane <= hi) ? v0 : NEG; \
    int u1i = 64 + lane; \
    p1 = (u1i >= lo && u1i <= hi) ? v1 : NEG; \
    p2 = (128 >= lo && 128 <= hi) ? v2 : NEG; \
}

// One wave per batch. Anti-diagonal wavefront held entirely in registers:
// lane l owns u=l and u=64+l; u=128 is replicated across all lanes.
// 4-deep software prefetch (named buffers A..D) hides skew-table load latency.
__global__ __launch_bounds__(64) void dp_kernel(
    const int* __restrict__ logit_lens, const int* __restrict__ y_lens,
    float* __restrict__ ws)
{
    const int b = blockIdx.x;
    const int lane = threadIdx.x;
    const int Tb = logit_lens[b];
    const int Ub = y_lens[b];
    const float* BL = ws + BLANK_SKEW_OFF + (size_t)b * SKD * U1;
    const float* EM = ws + EMIT_SKEW_OFF + (size_t)b * SKD * U1;
    const float NEG = -__builtin_inff();

    float p0 = (lane == 0) ? 0.0f : NEG;
    float p1 = NEG;
    float p2 = NEG;

    const int dend = Tb - 1 + Ub;

    float Ab0, Ab1, Ab2, Ae0, Ae1, Ae2;
    float Bb0, Bb1, Bb2, Be0, Be1, Be2;
    float Cb0, Cb1, Cb2, Ce0, Ce1, Ce2;
    float Db0, Db1, Db2, De0, De1, De2;

    LOADD(A, 1);
    LOADD(B, (2 > dend ? dend : 2));
    LOADD(C, (3 > dend ? dend : 3));
    LOADD(D, (4 > dend ? dend : 4));

    int d = 1;
    for (; d + 3 <= dend; d += 4) {
        COMPUTE(A, d);     { int dn = d + 4 > dend ? dend : d + 4; LOADD(A, dn); }
        COMPUTE(B, d + 1); { int dn = d + 5 > dend ? dend : d + 5; LOADD(B, dn); }
        COMPUTE(C, d + 2); { int dn = d + 6 > dend ? dend : d + 6; LOADD(C, dn); }
        COMPUTE(D, d + 3); { int dn = d + 7 > dend ? dend : d + 7; LOADD(D, dn); }
    }
    if (d <= dend) { COMPUTE(A, d); d++; }
    if (d <= dend) { COMPUTE(B, d); d++; }
    if (d <= dend) { COMPUTE(C, d); d++; }

    float a;
    if (Ub < 64)       a = __shfl(p0, Ub);
    else if (Ub < 128) a = __shfl(p1, Ub - 64);
    else               a = p2;                 // replicated across lanes
    if (lane == 0) {
        float blk = BL[(size_t)dend * U1 + Ub];
        ws[RES_OFF + b] = -(a + blk);
    }
}

__global__ void mean_kernel(const float* __restrict__ res, float* __restrict__ out)
{
    if (threadIdx.x == 0) {
        float s = 0.0f;
        #pragma unroll
        for (int i = 0; i < Bb; ++i) s += res[i];
        out[0] = s * (1.0f / Bb);
    }
}

extern "C" void kernel_launch(void* const* d_in, const int* in_sizes, int n_in,
                              void* d_out, int out_size, void* d_ws, size_t ws_size,
                              hipStream_t stream) {
    const float* logits     = (const float*)d_in[0];
    const int*   y          = (const int*)d_in[1];
    const int*   logit_lens = (const int*)d_in[2];
    const int*   y_lens     = (const int*)d_in[3];
    float* ws  = (float*)d_ws;
    float* out = (float*)d_out;

    const int rows = Bb * Tt * U1;             // 528384 rows, 8 rows/block
    lse_kernel<<<rows / 8, 256, 0, stream>>>(logits, y, ws);
    dp_kernel<<<Bb, 64, 0, stream>>>(logit_lens, y_lens, ws);
    mean_kernel<<<1, 64, 0, stream>>>(ws + RES_OFF, out);
}

// Round 4
// 140.684 us; speedup vs baseline: 3.9481x; 2.1147x over previous
//
#include <hip/hip_runtime.h>

#define Bb 8
#define Tt 512
#define Uu 128
#define U1 129
#define Vv 128
#define SKD 640
#define ROWF 260                       // floats per packed row: 129 float2 slots + pad (16B-aligned rows)
#define PKSZ ((size_t)SKD * ROWF)      // per-batch floats
#define RES_OFF ((size_t)Bb * PKSZ)

#define NEGI (-__builtin_inff())
#define K_INVLN2 1.4426950408889634f
#define K_LN2    0.6931471805599453f

__device__ __forceinline__ float fexp2(float x) {
    float r; asm("v_exp_f32 %0, %1" : "=v"(r) : "v"(x)); return r;
}
__device__ __forceinline__ float flog2(float x) {
    float r; asm("v_log_f32 %0, %1" : "=v"(r) : "v"(x)); return r;
}

// Packed skew table PK[b][r][slot] (float2 {bl, em} per slot), log2 domain.
// Reader (DP diag d) reads row r = d-1:
//   slot u .x = blank(t-1, u)  with t = d-u   -> blank(t',u') stored at row t'+u',   slot u'
//   slot u .y = emit (t, u-1)  with t = d-u   -> emit (t',u') stored at row t'+u',   slot u'+1
//   slot 0 .y = -inf sentinel (no left neighbor), rows 0..511
__global__ __launch_bounds__(256) void lse_kernel(
    const float* __restrict__ logits, const int* __restrict__ y,
    float* __restrict__ ws)
{
    const int wid  = threadIdx.x >> 6;
    const int lane = threadIdx.x & 63;
    const int half = lane >> 5;
    const int hl   = lane & 31;

    const long long row = (long long)blockIdx.x * 8 + wid * 2 + half;
    const int TU = Tt * U1;
    int b   = (int)(row / TU);
    int rem = (int)(row - (long long)b * TU);
    int t   = rem / U1;
    int u   = rem - t * U1;

    const float* p = logits + row * Vv + hl * 4;
    float4 v = *(const float4*)p;

    float m = fmaxf(fmaxf(v.x, v.y), fmaxf(v.z, v.w));
    #pragma unroll
    for (int off = 16; off; off >>= 1)
        m = fmaxf(m, __shfl_xor(m, off));
    float s = fexp2((v.x - m) * K_INVLN2) + fexp2((v.y - m) * K_INVLN2)
            + fexp2((v.z - m) * K_INVLN2) + fexp2((v.w - m) * K_INVLN2);
    #pragma unroll
    for (int off = 16; off; off >>= 1)
        s += __shfl_xor(s, off);
    float lse2 = m * K_INVLN2 + flog2(s);   // log2(sum_v exp(logit_v))

    float* PK = ws + (size_t)b * PKSZ + (size_t)(t + u) * ROWF;
    if (hl == 0) {
        PK[2 * u] = v.x * K_INVLN2 - lse2;            // blank(t,u) -> row t+u, slot u .x
        if (u == 0) PK[1] = NEGI;                     // row t, slot 0 .y = -inf sentinel
    }
    if (u < Uu) {
        int yv = y[b * Uu + u];                       // in [1, V)
        if (hl == (yv >> 2)) {
            int c = yv & 3;
            float ev = (c == 0) ? v.x : (c == 1) ? v.y : (c == 2) ? v.z : v.w;
            PK[2 * (u + 1) + 1] = ev * K_INVLN2 - lse2;   // emit(t,u) -> row t+u, slot u+1 .y
        }
    }
}

__device__ __forceinline__ float lae2(float x, float y) {
    float mx = fmaxf(x, y), mn = fminf(x, y);
    float r = mx + flog2(1.0f + fexp2(mn - mx));
    return (mx == NEGI) ? NEGI : r;                   // guard NaN when both -inf
}

// whole-wave rotate: lane i <- lane i-1 (mod 64), at VALU latency via DPP
template<int CTRL>
__device__ __forceinline__ float rot1(float x) {
    int i = __builtin_bit_cast(int, x);
    i = __builtin_amdgcn_update_dpp(i, i, CTRL, 0xF, 0xF, true);
    return __builtin_bit_cast(float, i);
}

template<int CTRL>
__device__ __forceinline__ void dp_body(int b, int lane, int Tb, int Ub,
                                        float* __restrict__ ws)
{
    const float* PK = ws + (size_t)b * PKSZ;
    int zv; asm volatile("v_mov_b32 %0, 0" : "=v"(zv));  // opaque 0: force VMEM (not SMEM) loads

    // lane l owns slots u=2l (px), u=2l+1 (py); slot 128 extracted from lane 0's p2.
    float px = (lane == 0) ? 0.0f : NEGI;
    float py = NEGI, p2 = NEGI;
    const int dend = Tb - 1 + Ub;    // in [319, 639]

    float4 Q0,Q1,Q2,Q3,Q4,Q5,Q6,Q7,Q8,Q9,Q10,Q11,Q12,Q13,Q14,Q15;
    float2 R0,R1,R2,R3,R4,R5,R6,R7,R8,R9,R10,R11,R12,R13,R14,R15;

#define LOADQ(i, dd) { const float* rb = PK + (size_t)((dd) - 1) * ROWF; \
    Q##i = *(const float4*)(rb + lane * 4); \
    R##i = *(const float2*)(rb + 256 + zv); }

#define COMP(i) { float pm = rot1<CTRL>(py); \
    float nx = lae2(px + Q##i.x, pm + Q##i.y); \
    float ny = lae2(py + Q##i.z, px + Q##i.w); \
    float n2 = lae2(p2 + R##i.x, pm + R##i.y); \
    px = nx; py = ny; p2 = n2; }

    LOADQ(0,1)  LOADQ(1,2)  LOADQ(2,3)  LOADQ(3,4)
    LOADQ(4,5)  LOADQ(5,6)  LOADQ(6,7)  LOADQ(7,8)
    LOADQ(8,9)  LOADQ(9,10) LOADQ(10,11) LOADQ(11,12)
    LOADQ(12,13) LOADQ(13,14) LOADQ(14,15) LOADQ(15,16)

    int d = 1;
#define STEP(i, ofs) { COMP(i); int dn = d + 16 + ofs; dn = dn > dend ? dend : dn; LOADQ(i, dn); }
    for (; d + 15 <= dend; d += 16) {
        STEP(0,0)  STEP(1,1)  STEP(2,2)  STEP(3,3)
        STEP(4,4)  STEP(5,5)  STEP(6,6)  STEP(7,7)
        STEP(8,8)  STEP(9,9)  STEP(10,10) STEP(11,11)
        STEP(12,12) STEP(13,13) STEP(14,14) STEP(15,15)
    }
#define TAIL(i) if (d <= dend) { COMP(i); d++; }
    TAIL(0) TAIL(1) TAIL(2) TAIL(3) TAIL(4) TAIL(5) TAIL(6) TAIL(7)
    TAIL(8) TAIL(9) TAIL(10) TAIL(11) TAIL(12) TAIL(13) TAIL(14)

    float a;
    if (Ub == 128) {
        a = __shfl(p2, 0);
    } else {
        float ax = __shfl(px, Ub >> 1);
        float ay = __shfl(py, Ub >> 1);
        a = (Ub & 1) ? ay : ax;
    }
    if (lane == 0) {
        float blk = PK[(size_t)dend * ROWF + 2 * Ub];  // blank(Tb-1, Ub), log2 domain
        ws[RES_OFF + b] = -(a + blk) * K_LN2;
    }
#undef LOADQ
#undef COMP
#undef STEP
#undef TAIL
}

__global__ __launch_bounds__(64) void dp_kernel(
    const int* __restrict__ logit_lens, const int* __restrict__ y_lens,
    float* __restrict__ ws)
{
    const int b = blockIdx.x;
    const int lane = threadIdx.x;
    const int Tb = logit_lens[b];
    const int Ub = y_lens[b];
    // runtime hedge on DPP rotate direction: pick the ctrl that does lane i <- lane i-1
    int li = lane;
    int rr = __builtin_amdgcn_update_dpp(li, li, 0x13C /*WAVE_ROR1*/, 0xF, 0xF, true);
    if (rr == ((lane + 63) & 63)) dp_body<0x13C>(b, lane, Tb, Ub, ws);
    else                          dp_body<0x134 /*WAVE_ROL1*/>(b, lane, Tb, Ub, ws);
}

__global__ void mean_kernel(const float* __restrict__ res, float* __restrict__ out)
{
    if (threadIdx.x == 0) {
        float s = 0.0f;
        #pragma unroll
        for (int i = 0; i < Bb; ++i) s += res[i];
        out[0] = s * (1.0f / Bb);
    }
}

extern "C" void kernel_launch(void* const* d_in, const int* in_sizes, int n_in,
                              void* d_out, int out_size, void* d_ws, size_t ws_size,
                              hipStream_t stream) {
    const float* logits     = (const float*)d_in[0];
    const int*   y          = (const int*)d_in[1];
    const int*   logit_lens = (const int*)d_in[2];
    const int*   y_lens     = (const int*)d_in[3];
    float* ws  = (float*)d_ws;
    float* out = (float*)d_out;

    const int rows = Bb * Tt * U1;             // 528384 rows, 8 rows/block
    lse_kernel<<<rows / 8, 256, 0, stream>>>(logits, y, ws);
    dp_kernel<<<Bb, 64, 0, stream>>>(logit_lens, y_lens, ws);
    mean_kernel<<<1, 64, 0, stream>>>(ws + RES_OFF, out);
}